// Round 16
// baseline (129.155 us; speedup 1.0000x reference)
//
#include <hip/hip_runtime.h>
#include <hip/hip_fp16.h>

#define NN 50000
#define NE 800000
#define D  128
#define NB 391                 // node buckets of 128
#define NS 256                 // sorter blocks
#define EPS 3125               // edges per sorter (NS*EPS == NE)
#define EPB (2 * EPS)          // 6250 directed entries per sorter
#define SN (NB * NS)           // 100096 scan elements
#define SCB 1024
#define NSB ((SN + SCB - 1) / SCB)   // 98
#define LCAP 5632              // csr2 LDS staging capacity (mean 4092, +10 sigma)

// ---- main-path ws layout (bytes) ----
#define OFF_SLAB 0             // int2[2E]      12,800,000
#define OFF_XW   0             // ushort[NN*D]  12,800,000 (row-major; aliases dead slab)
#define OFF_CSR4 12800000      // uint[2E]       6,400,000
#define OFF_HIST 19200000      // int[SN]          400,384
#define OFF_BASE 19600384      // int[SN]          400,384
#define OFF_BSUM 20000768      // int[NSB]             512
#define OFF_ROW  20001280      // int[NN+1]        200,004
#define OFF_WF   20201344      // ushort[128*128]   32,768 (W bf16 fragments)
#define NEED_A   20234112

// ---- fallback ws layout ----
#define OFF_CNT  0
#define OFF_ROWF 200704
#define OFF_CUR  401408
#define OFF_CSR8 602112

typedef float v2f  __attribute__((ext_vector_type(2)));
typedef __attribute__((ext_vector_type(8))) short bf16x8;
typedef __attribute__((ext_vector_type(4))) float f32x4;

__device__ __forceinline__ float bf_lo(unsigned int v) { return __uint_as_float(v << 16); }
__device__ __forceinline__ float bf_hi(unsigned int v) { return __uint_as_float(v & 0xffff0000u); }
__device__ __forceinline__ float wdec(unsigned int v) {
    return __half2float(__ushort_as_half((unsigned short)(v >> 16)));
}
__device__ __forceinline__ unsigned short bf16rne(float f) {
    unsigned int b = __float_as_uint(f);
    return (unsigned short)((b + 0x7fffu + ((b >> 16) & 1u)) >> 16);
}

// K1: per-sorter histogram over 391 buckets (LDS), b-major output
__global__ __launch_bounds__(256) void gc_shist(
    const int2* __restrict__ edges, int* __restrict__ histT)
{
    __shared__ int h[NB];
    const int s = blockIdx.x;
    for (int i = threadIdx.x; i < NB; i += 256) h[i] = 0;
    __syncthreads();
    const int e0 = s * EPS;
    for (int i = threadIdx.x; i < EPS; i += 256) {
        int2 p = edges[e0 + i];
        atomicAdd(&h[p.y >> 7], 1);
        atomicAdd(&h[p.x >> 7], 1);
    }
    __syncthreads();
    for (int b = threadIdx.x; b < NB; b += 256) histT[b * NS + s] = h[b];
}

// K2a/b/c: hierarchical exclusive scan over SN elements
__global__ __launch_bounds__(256) void gc_scanA(
    const int* __restrict__ in, int* __restrict__ bsum)
{
    __shared__ int red[256];
    int base = blockIdx.x * SCB;
    int s = 0;
    for (int i = threadIdx.x; i < SCB; i += 256) {
        int idx = base + i;
        s += (idx < SN) ? in[idx] : 0;
    }
    red[threadIdx.x] = s;
    __syncthreads();
    for (int off = 128; off > 0; off >>= 1) {
        if (threadIdx.x < off) red[threadIdx.x] += red[threadIdx.x + off];
        __syncthreads();
    }
    if (threadIdx.x == 0) bsum[blockIdx.x] = red[0];
}

__global__ __launch_bounds__(1024) void gc_scanB(int* __restrict__ bsum)
{
    __shared__ int part[1024];
    int t = threadIdx.x;
    int v = (t < NSB) ? bsum[t] : 0;
    part[t] = v;
    __syncthreads();
    for (int off = 1; off < 1024; off <<= 1) {
        int x = (t >= off) ? part[t - off] : 0;
        __syncthreads();
        part[t] += x;
        __syncthreads();
    }
    if (t < NSB) bsum[t] = part[t] - v;
}

__global__ __launch_bounds__(256) void gc_scanC(
    const int* __restrict__ in, const int* __restrict__ bsum,
    int* __restrict__ baseT)
{
    __shared__ int part[256];
    int base = blockIdx.x * SCB;
    int idx0 = base + threadIdx.x * 4;
    int4 v = make_int4(0, 0, 0, 0);
    if (idx0 + 3 < SN) v = *reinterpret_cast<const int4*>(in + idx0);
    int s = v.x + v.y + v.z + v.w;
    part[threadIdx.x] = s;
    __syncthreads();
    for (int off = 1; off < 256; off <<= 1) {
        int x = (threadIdx.x >= off) ? part[threadIdx.x - off] : 0;
        __syncthreads();
        part[threadIdx.x] += x;
        __syncthreads();
    }
    int run = bsum[blockIdx.x] + part[threadIdx.x] - s;
    if (idx0 + 3 < SN)
        *reinterpret_cast<int4*>(baseT + idx0) =
            make_int4(run, run + v.x, run + v.x + v.y, run + v.x + v.y + v.z);
}

// K3: LDS-staged scatter. Block builds its full 6250-entry bucket-ordered
// permutation in LDS, then writes out with consecutive lanes -> consecutive
// global addresses (coalesced), eliminating 64-line-per-instruction stores.
__global__ __launch_bounds__(256) void gc_sscat2(
    const int2* __restrict__ edges, const float* __restrict__ wts,
    const int* __restrict__ baseT, int2* __restrict__ slab)
{
    __shared__ int2 ebuf[EPB];         // 50,000 B
    __shared__ int  sc[512];           // padded inclusive-scan buffer
    __shared__ int  lbE[NB + 1];       // exclusive starts + total
    __shared__ int  cur[NB];
    __shared__ int  gb[NB];            // global chunk bases for this sorter

    const int s   = blockIdx.x;
    const int tid = threadIdx.x;
    const int e0  = s * EPS;

    sc[tid] = 0; sc[tid + 256] = 0;
    __syncthreads();

    // phase A: local histogram
    for (int i = tid; i < EPS; i += 256) {
        int2 p = edges[e0 + i];
        atomicAdd(&sc[p.y >> 7], 1);
        atomicAdd(&sc[p.x >> 7], 1);
    }
    // preload global bases
    for (int b = tid; b < NB; b += 256) gb[b] = baseT[b * NS + s];
    __syncthreads();

    int own0 = sc[tid], own1 = sc[tid + 256];
    // phase B: inclusive scan over 512 (2 slots/thread)
    for (int off = 1; off < 512; off <<= 1) {
        int v0 = (tid >= off) ? sc[tid - off] : 0;
        int v1 = (tid + 256 >= off) ? sc[tid + 256 - off] : 0;
        __syncthreads();
        sc[tid] += v0; sc[tid + 256] += v1;
        __syncthreads();
    }
    if (tid < NB)       { lbE[tid] = sc[tid] - own0;       cur[tid] = lbE[tid]; }
    int t1 = tid + 256;
    if (t1 < NB)        { lbE[t1]  = sc[t1] - own1;        cur[t1]  = lbE[t1]; }
    if (tid == 0) lbE[NB] = EPB;
    __syncthreads();

    // phase C: scatter entries into LDS (random LDS writes are cheap)
    for (int i = tid; i < EPS; i += 256) {
        int2 p = edges[e0 + i];
        int wb = __float_as_int(wts[e0 + i]);
        int b = p.y >> 7;
        int pos = atomicAdd(&cur[b], 1);
        ebuf[pos] = make_int2(p.x | ((p.y & 127) << 16), wb);
        b = p.x >> 7;
        pos = atomicAdd(&cur[b], 1);
        ebuf[pos] = make_int2(p.y | ((p.x & 127) << 16), wb);
    }
    __syncthreads();

    // phase D: coalesced write-out; binary search maps idx -> bucket
    for (int idx = tid; idx < EPB; idx += 256) {
        int lo = 0, hi = NB - 1;
        while (lo < hi) {
            int mid = (lo + hi + 1) >> 1;
            if (lbE[mid] <= idx) lo = mid; else hi = mid - 1;
        }
        slab[gb[lo] + (idx - lbE[lo])] = ebuf[idx];
    }
}

// K4: per-bucket CSR build, LDS-staged for coalesced csr4 writes.
__global__ __launch_bounds__(256) void gc_csr2(
    const int* __restrict__ baseT, const int2* __restrict__ slab,
    int* __restrict__ row_start, unsigned int* __restrict__ csr4)
{
    __shared__ int ncnt[128], ncur[128], part[128];
    __shared__ unsigned int cbuf[LCAP];    // 22.5 KB
    const int tid = threadIdx.x;
    const int b = blockIdx.x;
    const int start = baseT[b * NS];
    const int end = (b == NB - 1) ? (2 * NE) : baseT[(b + 1) * NS];
    const int sz = end - start;

    if (tid < 128) ncnt[tid] = 0;
    __syncthreads();

    for (int j = start + tid; j < end; j += 256)
        atomicAdd(&ncnt[(slab[j].x >> 16) & 127], 1);
    __syncthreads();

    if (tid < 128) part[tid] = ncnt[tid];
    __syncthreads();
    for (int off = 1; off < 128; off <<= 1) {
        int v = 0;
        if (tid < 128 && tid >= off) v = part[tid - off];
        __syncthreads();
        if (tid < 128) part[tid] += v;
        __syncthreads();
    }
    if (tid < 128) {
        int stl = part[tid] - ncnt[tid];       // local exclusive start
        int n = b * 128 + tid;
        if (n < NN) row_start[n] = start + stl;
        ncur[tid] = stl;
    }
    if (b == 0 && tid == 0) row_start[NN] = 2 * NE;
    __syncthreads();

    if (sz <= LCAP) {
        // staged: scatter into LDS, then coalesced burst
        for (int j = start + tid; j < end; j += 256) {
            int2 en = slab[j];
            int dl = (en.x >> 16) & 127;
            unsigned int hb =
                (unsigned int)__half_as_ushort(__float2half_rn(__int_as_float(en.y))) << 16;
            int pos = atomicAdd(&ncur[dl], 1);
            cbuf[pos] = (unsigned int)(en.x & 0xffff) | hb;
        }
        __syncthreads();
        for (int idx = tid; idx < sz; idx += 256)
            csr4[start + idx] = cbuf[idx];
    } else {
        // fallback: direct global scatter (statistically unreachable)
        for (int j = start + tid; j < end; j += 256) {
            int2 en = slab[j];
            int dl = (en.x >> 16) & 127;
            unsigned int hb =
                (unsigned int)__half_as_ushort(__float2half_rn(__int_as_float(en.y))) << 16;
            int pos = atomicAdd(&ncur[dl], 1);
            csr4[start + pos] = (unsigned int)(en.x & 0xffff) | hb;
        }
    }
}

// K5a: pack W (fp32 row-major [k][n]) into MFMA B-fragment order, bf16.
__global__ __launch_bounds__(256) void gc_wfrag(
    const float* __restrict__ Wm, unsigned short* __restrict__ wf)
{
    int t = blockIdx.x * 256 + threadIdx.x;      // 16384 total
    int j    = t & 7;
    int lane = (t >> 3) & 63;
    int nt   = (t >> 9) & 7;
    int ki   = t >> 12;
    int k = ki * 32 + (lane >> 4) * 8 + j;
    int n = nt * 16 + (lane & 15);
    wf[t] = bf16rne(Wm[k * D + n]);
}

// K5b: XW = X @ W via MFMA 16x16x32 bf16. 4 waves/block, 16 rows/wave.
__global__ __launch_bounds__(256) void gc_gemm_mfma(
    const float* __restrict__ X, const unsigned short* __restrict__ wf,
    unsigned short* __restrict__ dst)
{
    const int lane = threadIdx.x & 63;
    const int wave = threadIdx.x >> 6;
    const int rbase = blockIdx.x * 64 + wave * 16;
    const int r  = lane & 15;
    const int kb = lane >> 4;

    f32x4 acc[8];
    #pragma unroll
    for (int i = 0; i < 8; ++i) acc[i] = f32x4{0.f, 0.f, 0.f, 0.f};

    const bf16x8* wfv = reinterpret_cast<const bf16x8*>(wf);
    const int row = rbase + r;
    const bool rok = row < NN;

    #pragma unroll
    for (int ki = 0; ki < 4; ++ki) {
        float4 a0 = make_float4(0.f, 0.f, 0.f, 0.f);
        float4 a1 = make_float4(0.f, 0.f, 0.f, 0.f);
        if (rok) {
            const float4* xp = reinterpret_cast<const float4*>(
                X + (size_t)row * D + ki * 32 + kb * 8);
            a0 = xp[0];
            a1 = xp[1];
        }
        bf16x8 af;
        af[0] = (short)bf16rne(a0.x); af[1] = (short)bf16rne(a0.y);
        af[2] = (short)bf16rne(a0.z); af[3] = (short)bf16rne(a0.w);
        af[4] = (short)bf16rne(a1.x); af[5] = (short)bf16rne(a1.y);
        af[6] = (short)bf16rne(a1.z); af[7] = (short)bf16rne(a1.w);
        #pragma unroll
        for (int nt = 0; nt < 8; ++nt) {
            bf16x8 bf = wfv[(ki * 8 + nt) * 64 + lane];
            acc[nt] = __builtin_amdgcn_mfma_f32_16x16x32_bf16(af, bf, acc[nt], 0, 0, 0);
        }
    }

    const int orow0 = rbase + kb * 4;
    #pragma unroll
    for (int nt = 0; nt < 8; ++nt) {
        #pragma unroll
        for (int reg = 0; reg < 4; ++reg) {
            int orow = orow0 + reg;
            if (orow < NN)
                dst[(size_t)orow * D + nt * 16 + r] = bf16rne(acc[nt][reg]);
        }
    }
}

// K6: gather bf16 rows, wave per node, 8x unroll, 32-bit addressing,
// packed-f32 accumulation.
__global__ __launch_bounds__(256) void gc_gather4(
    const int* __restrict__ row_start, const unsigned int* __restrict__ csr4,
    const unsigned int* __restrict__ F, float* __restrict__ out)
{
    int wid  = (blockIdx.x * 256 + threadIdx.x) >> 6;
    unsigned int lane = threadIdx.x & 63;
    if (wid >= NN) return;
    int j   = row_start[wid];
    int end = row_start[wid + 1];
    v2f acc = {0.f, 0.f};
    float dw = 0.f;
    for (; j + 8 <= end; j += 8) {
        unsigned int e0 = csr4[j],     e1 = csr4[j + 1];
        unsigned int e2 = csr4[j + 2], e3 = csr4[j + 3];
        unsigned int e4 = csr4[j + 4], e5 = csr4[j + 5];
        unsigned int e6 = csr4[j + 6], e7 = csr4[j + 7];
        unsigned int v0 = F[((e0 & 0xffffu) << 6) | lane];
        unsigned int v1 = F[((e1 & 0xffffu) << 6) | lane];
        unsigned int v2 = F[((e2 & 0xffffu) << 6) | lane];
        unsigned int v3 = F[((e3 & 0xffffu) << 6) | lane];
        unsigned int v4 = F[((e4 & 0xffffu) << 6) | lane];
        unsigned int v5 = F[((e5 & 0xffffu) << 6) | lane];
        unsigned int v6 = F[((e6 & 0xffffu) << 6) | lane];
        unsigned int v7 = F[((e7 & 0xffffu) << 6) | lane];
        float w0 = wdec(e0), w1 = wdec(e1), w2 = wdec(e2), w3 = wdec(e3);
        float w4 = wdec(e4), w5 = wdec(e5), w6 = wdec(e6), w7 = wdec(e7);
        acc += w0 * v2f{bf_lo(v0), bf_hi(v0)};
        acc += w1 * v2f{bf_lo(v1), bf_hi(v1)};
        acc += w2 * v2f{bf_lo(v2), bf_hi(v2)};
        acc += w3 * v2f{bf_lo(v3), bf_hi(v3)};
        acc += w4 * v2f{bf_lo(v4), bf_hi(v4)};
        acc += w5 * v2f{bf_lo(v5), bf_hi(v5)};
        acc += w6 * v2f{bf_lo(v6), bf_hi(v6)};
        acc += w7 * v2f{bf_lo(v7), bf_hi(v7)};
        dw += (w0 + w1 + w2 + w3) + (w4 + w5 + w6 + w7);
    }
    for (; j < end; ++j) {
        unsigned int e0 = csr4[j];
        unsigned int v0 = F[((e0 & 0xffffu) << 6) | lane];
        float w0 = wdec(e0);
        acc += w0 * v2f{bf_lo(v0), bf_hi(v0)};
        dw += w0;
    }
    float inv = dw > 0.f ? 1.f / dw : 0.f;
    float2 r; r.x = acc.x * inv; r.y = acc.y * inv;
    reinterpret_cast<float2*>(out)[(size_t)wid * 64 + lane] = r;
}

// ======================= fallback path (fp32, small ws) ====================
__global__ __launch_bounds__(256) void gc_hist(
    const int2* __restrict__ edges, int* __restrict__ counts)
{
    int e = blockIdx.x * 256 + threadIdx.x;
    if (e >= NE) return;
    int2 p = edges[e];
    atomicAdd(counts + p.x, 1);
    atomicAdd(counts + p.y, 1);
}

__global__ __launch_bounds__(1024) void gc_scan(
    const int* __restrict__ counts, int* __restrict__ row_start,
    int* __restrict__ cursor)
{
    const int CHUNK = (NN + 1023) / 1024;
    __shared__ int part[1024];
    int t = threadIdx.x;
    int lo = t * CHUNK, hi = min(lo + CHUNK, NN);
    int s = 0;
    for (int i = lo; i < hi; ++i) s += counts[i];
    part[t] = s;
    __syncthreads();
    for (int off = 1; off < 1024; off <<= 1) {
        int v = (t >= off) ? part[t - off] : 0;
        __syncthreads();
        part[t] += v;
        __syncthreads();
    }
    int run = part[t] - s;
    for (int i = lo; i < hi; ++i) {
        int c = counts[i];
        row_start[i] = run;
        cursor[i]    = run;
        run += c;
    }
    if (t == 1023) row_start[NN] = part[1023];
}

__global__ __launch_bounds__(256) void gc_fill8(
    const int2* __restrict__ edges, const float* __restrict__ wts,
    int* __restrict__ cursor, int2* __restrict__ csr)
{
    int e = blockIdx.x * 256 + threadIdx.x;
    if (e >= NE) return;
    int2 p = edges[e];
    int wb = __float_as_int(wts[e]);
    int pos = atomicAdd(cursor + p.y, 1);
    csr[pos] = make_int2(p.x, wb);
    pos = atomicAdd(cursor + p.x, 1);
    csr[pos] = make_int2(p.y, wb);
}

__global__ __launch_bounds__(256) void gc_gather_f32(
    const int* __restrict__ row_start, const int2* __restrict__ csr,
    const float* __restrict__ F, float* __restrict__ out)
{
    int wid  = (blockIdx.x * 256 + threadIdx.x) >> 6;
    int lane = threadIdx.x & 63;
    if (wid >= NN) return;
    int j   = row_start[wid];
    int end = row_start[wid + 1];
    const float2* F2 = reinterpret_cast<const float2*>(F);
    float ax = 0.f, ay = 0.f, dw = 0.f;
    for (; j < end; ++j) {
        int2  cw = csr[j];
        float w  = __int_as_float(cw.y);
        float2 xv = F2[(size_t)cw.x * 64 + lane];
        ax = fmaf(w, xv.x, ax);
        ay = fmaf(w, xv.y, ay);
        dw += w;
    }
    float inv = dw > 0.f ? 1.f / dw : 0.f;
    float2 r; r.x = ax * inv; r.y = ay * inv;
    reinterpret_cast<float2*>(out)[(size_t)wid * 64 + lane] = r;
}

__global__ __launch_bounds__(256) void gc_gemm_f32(
    const float* __restrict__ src, float* __restrict__ dst,
    const float* __restrict__ Wm)
{
    __shared__ float Ws[D * D];
    __shared__ float axs[16 * D];
    const int tid = threadIdx.x;
    const int col = tid & 127;
    const int ty  = tid >> 7;
    const int rbase = blockIdx.x * 16;

    const float4* W4  = reinterpret_cast<const float4*>(Wm);
    float4*       Ws4 = reinterpret_cast<float4*>(Ws);
    #pragma unroll
    for (int i = 0; i < 16; ++i) Ws4[tid + i * 256] = W4[tid + i * 256];

    const float4* A4   = reinterpret_cast<const float4*>(src + (size_t)rbase * D);
    float4*       axs4 = reinterpret_cast<float4*>(axs);
    #pragma unroll
    for (int i = 0; i < 2; ++i) axs4[tid + i * 256] = A4[tid + i * 256];
    __syncthreads();

    float acc[8];
    #pragma unroll
    for (int i = 0; i < 8; ++i) acc[i] = 0.f;

    for (int k = 0; k < D; ++k) {
        float wv = Ws[k * D + col];
        #pragma unroll
        for (int i = 0; i < 8; ++i)
            acc[i] = fmaf(axs[(ty * 8 + i) * D + k], wv, acc[i]);
    }

    #pragma unroll
    for (int i = 0; i < 8; ++i)
        dst[(size_t)(rbase + ty * 8 + i) * D + col] = acc[i];
}

extern "C" void kernel_launch(void* const* d_in, const int* in_sizes, int n_in,
                              void* d_out, int out_size, void* d_ws, size_t ws_size,
                              hipStream_t stream) {
    const float* X     = (const float*)d_in[0];
    const int2*  edges = (const int2*)d_in[1];
    const float* wts   = (const float*)d_in[2];
    const float* Wm    = (const float*)d_in[3];
    float* out = (float*)d_out;
    char*  ws  = (char*)d_ws;

    const int eblocks = (NE + 255) / 256;

    if (ws_size >= NEED_A) {
        int2* slab  = (int2*)(ws + OFF_SLAB);
        unsigned int* csr4 = (unsigned int*)(ws + OFF_CSR4);
        int*  histT = (int*)(ws + OFF_HIST);
        int*  baseT = (int*)(ws + OFF_BASE);
        int*  bsum  = (int*)(ws + OFF_BSUM);
        int*  row   = (int*)(ws + OFF_ROW);
        unsigned short* wf = (unsigned short*)(ws + OFF_WF);
        unsigned short* xw = (unsigned short*)(ws + OFF_XW);   // aliases dead slab

        gc_shist<<<NS, 256, 0, stream>>>(edges, histT);
        gc_scanA<<<NSB, 256, 0, stream>>>(histT, bsum);
        gc_scanB<<<1, 1024, 0, stream>>>(bsum);
        gc_scanC<<<NSB, 256, 0, stream>>>(histT, bsum, baseT);
        gc_sscat2<<<NS, 256, 0, stream>>>(edges, wts, baseT, slab);
        gc_wfrag<<<64, 256, 0, stream>>>(Wm, wf);
        gc_csr2<<<NB, 256, 0, stream>>>(baseT, slab, row, csr4);
        gc_gemm_mfma<<<(NN + 63) / 64, 256, 0, stream>>>(X, wf, xw);  // overwrites slab
        gc_gather4<<<(NN * 64 + 255) / 256, 256, 0, stream>>>(
            row, csr4, (const unsigned int*)xw, out);
    } else {
        int*  counts    = (int*) (ws + OFF_CNT);
        int*  row_start = (int*) (ws + OFF_ROWF);
        int*  cursor    = (int*) (ws + OFF_CUR);
        int2* csr       = (int2*)(ws + OFF_CSR8);

        hipMemsetAsync(counts, 0, NN * sizeof(int), stream);
        gc_hist<<<eblocks, 256, 0, stream>>>(edges, counts);
        gc_scan<<<1, 1024, 0, stream>>>(counts, row_start, cursor);
        gc_fill8<<<eblocks, 256, 0, stream>>>(edges, wts, cursor, csr);
        gc_gather_f32<<<(NN * 64 + 255) / 256, 256, 0, stream>>>(row_start, csr, X, out);
        gc_gemm_f32<<<NN / 16, 256, 0, stream>>>(out, out, Wm);
    }
}

// Round 17
// 124.806 us; speedup vs baseline: 1.0348x; 1.0348x over previous
//
#include <hip/hip_runtime.h>
#include <hip/hip_fp16.h>

#define NN 50000
#define NE 800000
#define D  128
#define NB 391                 // node buckets of 128
#define NS 256                 // sorter blocks
#define EPS 3125               // edges per sorter (NS*EPS == NE)
#define SN (NB * NS)           // 100096 scan elements
#define SCB 1024
#define NSB ((SN + SCB - 1) / SCB)   // 98
#define NPASS 4                // gather feature chunks (32 cols each)
#define GPB 3125               // gather blocks per pass (50000*16/256)

// ---- main-path ws layout (bytes) ----
#define OFF_SLAB 0             // int2[2E]      12,800,000
#define OFF_XW   0             // ushort[4][NN][32] 12,800,000 (chunk-major; aliases dead slab)
#define OFF_CSR4 12800000      // uint[2E]       6,400,000
#define OFF_HIST 19200000      // int[SN]          400,384
#define OFF_BASE 19600384      // int[SN]          400,384
#define OFF_BSUM 20000768      // int[NSB]             512
#define OFF_ROW  20001280      // int[NN+1]        200,004
#define OFF_WF   20201344      // ushort[128*128]   32,768 (W bf16 fragments)
#define NEED_A   20234112

// ---- fallback ws layout ----
#define OFF_CNT  0
#define OFF_ROWF 200704
#define OFF_CUR  401408
#define OFF_CSR8 602112

typedef float v2f  __attribute__((ext_vector_type(2)));
typedef __attribute__((ext_vector_type(8))) short bf16x8;
typedef __attribute__((ext_vector_type(4))) float f32x4;

__device__ __forceinline__ float bf_lo(unsigned int v) { return __uint_as_float(v << 16); }
__device__ __forceinline__ float bf_hi(unsigned int v) { return __uint_as_float(v & 0xffff0000u); }
__device__ __forceinline__ float wdec(unsigned int v) {
    return __half2float(__ushort_as_half((unsigned short)(v >> 16)));
}
__device__ __forceinline__ unsigned short bf16rne(float f) {
    unsigned int b = __float_as_uint(f);
    return (unsigned short)((b + 0x7fffu + ((b >> 16) & 1u)) >> 16);
}

// K1: per-sorter histogram over 391 buckets (LDS), b-major output
__global__ __launch_bounds__(256) void gc_shist(
    const int2* __restrict__ edges, int* __restrict__ histT)
{
    __shared__ int h[NB];
    const int s = blockIdx.x;
    for (int i = threadIdx.x; i < NB; i += 256) h[i] = 0;
    __syncthreads();
    const int e0 = s * EPS;
    for (int i = threadIdx.x; i < EPS; i += 256) {
        int2 p = edges[e0 + i];
        atomicAdd(&h[p.y >> 7], 1);
        atomicAdd(&h[p.x >> 7], 1);
    }
    __syncthreads();
    for (int b = threadIdx.x; b < NB; b += 256) histT[b * NS + s] = h[b];
}

// K2a/b/c: hierarchical exclusive scan over SN elements
__global__ __launch_bounds__(256) void gc_scanA(
    const int* __restrict__ in, int* __restrict__ bsum)
{
    __shared__ int red[256];
    int base = blockIdx.x * SCB;
    int s = 0;
    for (int i = threadIdx.x; i < SCB; i += 256) {
        int idx = base + i;
        s += (idx < SN) ? in[idx] : 0;
    }
    red[threadIdx.x] = s;
    __syncthreads();
    for (int off = 128; off > 0; off >>= 1) {
        if (threadIdx.x < off) red[threadIdx.x] += red[threadIdx.x + off];
        __syncthreads();
    }
    if (threadIdx.x == 0) bsum[blockIdx.x] = red[0];
}

__global__ __launch_bounds__(1024) void gc_scanB(int* __restrict__ bsum)
{
    __shared__ int part[1024];
    int t = threadIdx.x;
    int v = (t < NSB) ? bsum[t] : 0;
    part[t] = v;
    __syncthreads();
    for (int off = 1; off < 1024; off <<= 1) {
        int x = (t >= off) ? part[t - off] : 0;
        __syncthreads();
        part[t] += x;
        __syncthreads();
    }
    if (t < NSB) bsum[t] = part[t] - v;
}

__global__ __launch_bounds__(256) void gc_scanC(
    const int* __restrict__ in, const int* __restrict__ bsum,
    int* __restrict__ baseT)
{
    __shared__ int part[256];
    int base = blockIdx.x * SCB;
    int idx0 = base + threadIdx.x * 4;
    int4 v = make_int4(0, 0, 0, 0);
    if (idx0 + 3 < SN) v = *reinterpret_cast<const int4*>(in + idx0);
    int s = v.x + v.y + v.z + v.w;
    part[threadIdx.x] = s;
    __syncthreads();
    for (int off = 1; off < 256; off <<= 1) {
        int x = (threadIdx.x >= off) ? part[threadIdx.x - off] : 0;
        __syncthreads();
        part[threadIdx.x] += x;
        __syncthreads();
    }
    int run = bsum[blockIdx.x] + part[threadIdx.x] - s;
    if (idx0 + 3 < SN)
        *reinterpret_cast<int4*>(baseT + idx0) =
            make_int4(run, run + v.x, run + v.x + v.y, run + v.x + v.y + v.z);
}

// K3: scatter entries into per-(sorter,bucket) contiguous chunks (R14-proven)
__global__ __launch_bounds__(256) void gc_sscat(
    const int2* __restrict__ edges, const float* __restrict__ wts,
    const int* __restrict__ baseT, int2* __restrict__ slab)
{
    __shared__ int cur[NB];
    const int s = blockIdx.x;
    for (int b = threadIdx.x; b < NB; b += 256) cur[b] = baseT[b * NS + s];
    __syncthreads();
    const int e0 = s * EPS;
    for (int i = threadIdx.x; i < EPS; i += 256) {
        int2 p = edges[e0 + i];
        int wb = __float_as_int(wts[e0 + i]);
        int b = p.y >> 7;
        int pos = atomicAdd(&cur[b], 1);
        slab[pos] = make_int2(p.x | ((p.y & 127) << 16), wb);
        b = p.x >> 7;
        pos = atomicAdd(&cur[b], 1);
        slab[pos] = make_int2(p.y | ((p.x & 127) << 16), wb);
    }
}

// K4: per-bucket CSR build from the contiguous bucket region (R14-proven)
__global__ __launch_bounds__(256) void gc_csr(
    const int* __restrict__ baseT, const int2* __restrict__ slab,
    int* __restrict__ row_start, unsigned int* __restrict__ csr4)
{
    __shared__ int ncnt[128], ncur[128], part[128];
    const int tid = threadIdx.x;
    const int b = blockIdx.x;
    const int start = baseT[b * NS];
    const int end = (b == NB - 1) ? (2 * NE) : baseT[(b + 1) * NS];

    if (tid < 128) ncnt[tid] = 0;
    __syncthreads();

    for (int j = start + tid; j < end; j += 256)
        atomicAdd(&ncnt[(slab[j].x >> 16) & 127], 1);
    __syncthreads();

    if (tid < 128) part[tid] = ncnt[tid];
    __syncthreads();
    for (int off = 1; off < 128; off <<= 1) {
        int v = 0;
        if (tid < 128 && tid >= off) v = part[tid - off];
        __syncthreads();
        if (tid < 128) part[tid] += v;
        __syncthreads();
    }
    if (tid < 128) {
        int st = start + part[tid] - ncnt[tid];
        int n = b * 128 + tid;
        if (n < NN) row_start[n] = st;
        ncur[tid] = st;
    }
    if (b == 0 && tid == 0) row_start[NN] = 2 * NE;
    __syncthreads();

    for (int j = start + tid; j < end; j += 256) {
        int2 en = slab[j];
        int dl = (en.x >> 16) & 127;
        unsigned int hb =
            (unsigned int)__half_as_ushort(__float2half_rn(__int_as_float(en.y))) << 16;
        int pos = atomicAdd(&ncur[dl], 1);
        csr4[pos] = (unsigned int)(en.x & 0xffff) | hb;
    }
}

// K5a: pack W (fp32 row-major [k][n]) into MFMA B-fragment order, bf16.
__global__ __launch_bounds__(256) void gc_wfrag(
    const float* __restrict__ Wm, unsigned short* __restrict__ wf)
{
    int t = blockIdx.x * 256 + threadIdx.x;      // 16384 total
    int j    = t & 7;
    int lane = (t >> 3) & 63;
    int nt   = (t >> 9) & 7;
    int ki   = t >> 12;
    int k = ki * 32 + (lane >> 4) * 8 + j;
    int n = nt * 16 + (lane & 15);
    wf[t] = bf16rne(Wm[k * D + n]);
}

// K5b: XW = X @ W via MFMA 16x16x32 bf16; CHUNK-MAJOR output
// XWc[chunk][node][32 cols], chunk = col>>5.
__global__ __launch_bounds__(256) void gc_gemm_mfma(
    const float* __restrict__ X, const unsigned short* __restrict__ wf,
    unsigned short* __restrict__ dst)
{
    const int lane = threadIdx.x & 63;
    const int wave = threadIdx.x >> 6;
    const int rbase = blockIdx.x * 64 + wave * 16;
    const int r  = lane & 15;
    const int kb = lane >> 4;

    f32x4 acc[8];
    #pragma unroll
    for (int i = 0; i < 8; ++i) acc[i] = f32x4{0.f, 0.f, 0.f, 0.f};

    const bf16x8* wfv = reinterpret_cast<const bf16x8*>(wf);
    const int row = rbase + r;
    const bool rok = row < NN;

    #pragma unroll
    for (int ki = 0; ki < 4; ++ki) {
        float4 a0 = make_float4(0.f, 0.f, 0.f, 0.f);
        float4 a1 = make_float4(0.f, 0.f, 0.f, 0.f);
        if (rok) {
            const float4* xp = reinterpret_cast<const float4*>(
                X + (size_t)row * D + ki * 32 + kb * 8);
            a0 = xp[0];
            a1 = xp[1];
        }
        bf16x8 af;
        af[0] = (short)bf16rne(a0.x); af[1] = (short)bf16rne(a0.y);
        af[2] = (short)bf16rne(a0.z); af[3] = (short)bf16rne(a0.w);
        af[4] = (short)bf16rne(a1.x); af[5] = (short)bf16rne(a1.y);
        af[6] = (short)bf16rne(a1.z); af[7] = (short)bf16rne(a1.w);
        #pragma unroll
        for (int nt = 0; nt < 8; ++nt) {
            bf16x8 bf = wfv[(ki * 8 + nt) * 64 + lane];
            acc[nt] = __builtin_amdgcn_mfma_f32_16x16x32_bf16(af, bf, acc[nt], 0, 0, 0);
        }
    }

    const int orow0 = rbase + kb * 4;
    #pragma unroll
    for (int nt = 0; nt < 8; ++nt) {
        const int col = nt * 16 + r;
        const size_t cbase = (size_t)(col >> 5) * (NN * 32) + (col & 31);
        #pragma unroll
        for (int reg = 0; reg < 4; ++reg) {
            int orow = orow0 + reg;
            if (orow < NN)
                dst[cbase + (size_t)orow * 32] = bf16rne(acc[nt][reg]);
        }
    }
}

// K6: 4-pass chunked gather. Pass g = blockIdx/GPB works on cols [32g,32g+32):
// working set NN*64B = 3.2 MB -> per-XCD L2 resident. 16 lanes per node
// (full 64B line per entry), lane c owns 2 cols (one packed uint).
__global__ __launch_bounds__(256) void gc_gather_p(
    const int* __restrict__ row_start, const unsigned int* __restrict__ csr4,
    const unsigned int* __restrict__ XWc, float* __restrict__ out)
{
    const int g  = blockIdx.x / GPB;
    const int nb = blockIdx.x - g * GPB;
    const int node = (nb * 256 + threadIdx.x) >> 4;   // 16 threads/node, exact
    const unsigned int c = threadIdx.x & 15;
    const unsigned int* F = XWc + (size_t)g * (NN * 16) + c;

    int j   = row_start[node];
    int end = row_start[node + 1];
    v2f acc = {0.f, 0.f};
    float dw = 0.f;
    for (; j + 4 <= end; j += 4) {
        unsigned int e0 = csr4[j],     e1 = csr4[j + 1];
        unsigned int e2 = csr4[j + 2], e3 = csr4[j + 3];
        unsigned int v0 = F[(e0 & 0xffffu) << 4];
        unsigned int v1 = F[(e1 & 0xffffu) << 4];
        unsigned int v2 = F[(e2 & 0xffffu) << 4];
        unsigned int v3 = F[(e3 & 0xffffu) << 4];
        float w0 = wdec(e0), w1 = wdec(e1), w2 = wdec(e2), w3 = wdec(e3);
        acc += w0 * v2f{bf_lo(v0), bf_hi(v0)};
        acc += w1 * v2f{bf_lo(v1), bf_hi(v1)};
        acc += w2 * v2f{bf_lo(v2), bf_hi(v2)};
        acc += w3 * v2f{bf_lo(v3), bf_hi(v3)};
        dw += (w0 + w1) + (w2 + w3);
    }
    for (; j < end; ++j) {
        unsigned int e0 = csr4[j];
        unsigned int v0 = F[(e0 & 0xffffu) << 4];
        float w0 = wdec(e0);
        acc += w0 * v2f{bf_lo(v0), bf_hi(v0)};
        dw += w0;
    }
    float inv = dw > 0.f ? 1.f / dw : 0.f;
    float2 r; r.x = acc.x * inv; r.y = acc.y * inv;
    reinterpret_cast<float2*>(out)[(size_t)node * 64 + g * 16 + c] = r;
}

// ======================= fallback path (fp32, small ws) ====================
__global__ __launch_bounds__(256) void gc_hist(
    const int2* __restrict__ edges, int* __restrict__ counts)
{
    int e = blockIdx.x * 256 + threadIdx.x;
    if (e >= NE) return;
    int2 p = edges[e];
    atomicAdd(counts + p.x, 1);
    atomicAdd(counts + p.y, 1);
}

__global__ __launch_bounds__(1024) void gc_scan(
    const int* __restrict__ counts, int* __restrict__ row_start,
    int* __restrict__ cursor)
{
    const int CHUNK = (NN + 1023) / 1024;
    __shared__ int part[1024];
    int t = threadIdx.x;
    int lo = t * CHUNK, hi = min(lo + CHUNK, NN);
    int s = 0;
    for (int i = lo; i < hi; ++i) s += counts[i];
    part[t] = s;
    __syncthreads();
    for (int off = 1; off < 1024; off <<= 1) {
        int v = (t >= off) ? part[t - off] : 0;
        __syncthreads();
        part[t] += v;
        __syncthreads();
    }
    int run = part[t] - s;
    for (int i = lo; i < hi; ++i) {
        int c = counts[i];
        row_start[i] = run;
        cursor[i]    = run;
        run += c;
    }
    if (t == 1023) row_start[NN] = part[1023];
}

__global__ __launch_bounds__(256) void gc_fill8(
    const int2* __restrict__ edges, const float* __restrict__ wts,
    int* __restrict__ cursor, int2* __restrict__ csr)
{
    int e = blockIdx.x * 256 + threadIdx.x;
    if (e >= NE) return;
    int2 p = edges[e];
    int wb = __float_as_int(wts[e]);
    int pos = atomicAdd(cursor + p.y, 1);
    csr[pos] = make_int2(p.x, wb);
    pos = atomicAdd(cursor + p.x, 1);
    csr[pos] = make_int2(p.y, wb);
}

__global__ __launch_bounds__(256) void gc_gather_f32(
    const int* __restrict__ row_start, const int2* __restrict__ csr,
    const float* __restrict__ F, float* __restrict__ out)
{
    int wid  = (blockIdx.x * 256 + threadIdx.x) >> 6;
    int lane = threadIdx.x & 63;
    if (wid >= NN) return;
    int j   = row_start[wid];
    int end = row_start[wid + 1];
    const float2* F2 = reinterpret_cast<const float2*>(F);
    float ax = 0.f, ay = 0.f, dw = 0.f;
    for (; j < end; ++j) {
        int2  cw = csr[j];
        float w  = __int_as_float(cw.y);
        float2 xv = F2[(size_t)cw.x * 64 + lane];
        ax = fmaf(w, xv.x, ax);
        ay = fmaf(w, xv.y, ay);
        dw += w;
    }
    float inv = dw > 0.f ? 1.f / dw : 0.f;
    float2 r; r.x = ax * inv; r.y = ay * inv;
    reinterpret_cast<float2*>(out)[(size_t)wid * 64 + lane] = r;
}

__global__ __launch_bounds__(256) void gc_gemm_f32(
    const float* __restrict__ src, float* __restrict__ dst,
    const float* __restrict__ Wm)
{
    __shared__ float Ws[D * D];
    __shared__ float axs[16 * D];
    const int tid = threadIdx.x;
    const int col = tid & 127;
    const int ty  = tid >> 7;
    const int rbase = blockIdx.x * 16;

    const float4* W4  = reinterpret_cast<const float4*>(Wm);
    float4*       Ws4 = reinterpret_cast<float4*>(Ws);
    #pragma unroll
    for (int i = 0; i < 16; ++i) Ws4[tid + i * 256] = W4[tid + i * 256];

    const float4* A4   = reinterpret_cast<const float4*>(src + (size_t)rbase * D);
    float4*       axs4 = reinterpret_cast<float4*>(axs);
    #pragma unroll
    for (int i = 0; i < 2; ++i) axs4[tid + i * 256] = A4[tid + i * 256];
    __syncthreads();

    float acc[8];
    #pragma unroll
    for (int i = 0; i < 8; ++i) acc[i] = 0.f;

    for (int k = 0; k < D; ++k) {
        float wv = Ws[k * D + col];
        #pragma unroll
        for (int i = 0; i < 8; ++i)
            acc[i] = fmaf(axs[(ty * 8 + i) * D + k], wv, acc[i]);
    }

    #pragma unroll
    for (int i = 0; i < 8; ++i)
        dst[(size_t)(rbase + ty * 8 + i) * D + col] = acc[i];
}

extern "C" void kernel_launch(void* const* d_in, const int* in_sizes, int n_in,
                              void* d_out, int out_size, void* d_ws, size_t ws_size,
                              hipStream_t stream) {
    const float* X     = (const float*)d_in[0];
    const int2*  edges = (const int2*)d_in[1];
    const float* wts   = (const float*)d_in[2];
    const float* Wm    = (const float*)d_in[3];
    float* out = (float*)d_out;
    char*  ws  = (char*)d_ws;

    const int eblocks = (NE + 255) / 256;

    if (ws_size >= NEED_A) {
        int2* slab  = (int2*)(ws + OFF_SLAB);
        unsigned int* csr4 = (unsigned int*)(ws + OFF_CSR4);
        int*  histT = (int*)(ws + OFF_HIST);
        int*  baseT = (int*)(ws + OFF_BASE);
        int*  bsum  = (int*)(ws + OFF_BSUM);
        int*  row   = (int*)(ws + OFF_ROW);
        unsigned short* wf = (unsigned short*)(ws + OFF_WF);
        unsigned short* xw = (unsigned short*)(ws + OFF_XW);   // aliases dead slab

        gc_shist<<<NS, 256, 0, stream>>>(edges, histT);
        gc_scanA<<<NSB, 256, 0, stream>>>(histT, bsum);
        gc_scanB<<<1, 1024, 0, stream>>>(bsum);
        gc_scanC<<<NSB, 256, 0, stream>>>(histT, bsum, baseT);
        gc_sscat<<<NS, 256, 0, stream>>>(edges, wts, baseT, slab);
        gc_wfrag<<<64, 256, 0, stream>>>(Wm, wf);
        gc_csr<<<NB, 256, 0, stream>>>(baseT, slab, row, csr4);
        gc_gemm_mfma<<<(NN + 63) / 64, 256, 0, stream>>>(X, wf, xw);  // overwrites slab
        gc_gather_p<<<NPASS * GPB, 256, 0, stream>>>(
            row, csr4, (const unsigned int*)xw, out);
    } else {
        int*  counts    = (int*) (ws + OFF_CNT);
        int*  row_start = (int*) (ws + OFF_ROWF);
        int*  cursor    = (int*) (ws + OFF_CUR);
        int2* csr       = (int2*)(ws + OFF_CSR8);

        hipMemsetAsync(counts, 0, NN * sizeof(int), stream);
        gc_hist<<<eblocks, 256, 0, stream>>>(edges, counts);
        gc_scan<<<1, 1024, 0, stream>>>(counts, row_start, cursor);
        gc_fill8<<<eblocks, 256, 0, stream>>>(edges, wts, cursor, csr);
        gc_gather_f32<<<(NN * 64 + 255) / 256, 256, 0, stream>>>(row_start, csr, X, out);
        gc_gemm_f32<<<NN / 16, 256, 0, stream>>>(out, out, Wm);
    }
}

// Round 18
// 108.873 us; speedup vs baseline: 1.1863x; 1.1463x over previous
//
#include <hip/hip_runtime.h>
#include <hip/hip_fp16.h>

#define NN 50000
#define NE 800000
#define D  128
#define NB 391                 // node buckets of 128
#define NS 256                 // sorter blocks
#define EPS 3125               // edges per sorter (NS*EPS == NE)
#define SN (NB * NS)           // 100096 scan elements
#define SCB 1024
#define NSB ((SN + SCB - 1) / SCB)   // 98

// ---- main-path ws layout (bytes) ----
#define OFF_SLAB 0             // int2[2E]      12,800,000
#define OFF_XW   0             // ushort[NN*D]  12,800,000 (row-major; aliases dead slab)
#define OFF_CSR4 12800000      // uint[2E]       6,400,000
#define OFF_HIST 19200000      // int[SN]          400,384
#define OFF_BASE 19600384      // int[SN]          400,384
#define OFF_BSUM 20000768      // int[NSB]             512
#define OFF_ROW  20001280      // int[NN+1]        200,004
#define OFF_WF   20201344      // ushort[128*128]   32,768 (W bf16 fragments)
#define NEED_A   20234112

// ---- fallback ws layout ----
#define OFF_CNT  0
#define OFF_ROWF 200704
#define OFF_CUR  401408
#define OFF_CSR8 602112

typedef float v2f  __attribute__((ext_vector_type(2)));
typedef __attribute__((ext_vector_type(8))) short bf16x8;
typedef __attribute__((ext_vector_type(4))) float f32x4;

__device__ __forceinline__ float bf_lo(unsigned int v) { return __uint_as_float(v << 16); }
__device__ __forceinline__ float bf_hi(unsigned int v) { return __uint_as_float(v & 0xffff0000u); }
__device__ __forceinline__ float wdec(unsigned int v) {
    return __half2float(__ushort_as_half((unsigned short)(v >> 16)));
}
__device__ __forceinline__ unsigned short bf16rne(float f) {
    unsigned int b = __float_as_uint(f);
    return (unsigned short)((b + 0x7fffu + ((b >> 16) & 1u)) >> 16);
}

// K1: per-sorter histogram over 391 buckets (LDS), b-major output
__global__ __launch_bounds__(256) void gc_shist(
    const int2* __restrict__ edges, int* __restrict__ histT)
{
    __shared__ int h[NB];
    const int s = blockIdx.x;
    for (int i = threadIdx.x; i < NB; i += 256) h[i] = 0;
    __syncthreads();
    const int e0 = s * EPS;
    for (int i = threadIdx.x; i < EPS; i += 256) {
        int2 p = edges[e0 + i];
        atomicAdd(&h[p.y >> 7], 1);
        atomicAdd(&h[p.x >> 7], 1);
    }
    __syncthreads();
    for (int b = threadIdx.x; b < NB; b += 256) histT[b * NS + s] = h[b];
}

// K2a: per-chunk partial sums
__global__ __launch_bounds__(256) void gc_scanA(
    const int* __restrict__ in, int* __restrict__ bsum)
{
    __shared__ int red[256];
    int base = blockIdx.x * SCB;
    int s = 0;
    for (int i = threadIdx.x; i < SCB; i += 256) {
        int idx = base + i;
        s += (idx < SN) ? in[idx] : 0;
    }
    red[threadIdx.x] = s;
    __syncthreads();
    for (int off = 128; off > 0; off >>= 1) {
        if (threadIdx.x < off) red[threadIdx.x] += red[threadIdx.x + off];
        __syncthreads();
    }
    if (threadIdx.x == 0) bsum[blockIdx.x] = red[0];
}

// K2b: per-chunk local scan + INLINE scan of the 98 block sums (no scanB launch)
__global__ __launch_bounds__(256) void gc_scanC(
    const int* __restrict__ in, const int* __restrict__ bsum,
    int* __restrict__ baseT)
{
    __shared__ int part[256];
    __shared__ int sb[128];
    const int t = threadIdx.x;

    // redundant per-block scan of the 98 block sums (cheap, removes a dispatch)
    int own = 0;
    if (t < 128) {
        own = (t < NSB) ? bsum[t] : 0;
        sb[t] = own;
    }
    __syncthreads();
    for (int off = 1; off < 128; off <<= 1) {
        int v = (t < 128 && t >= off) ? sb[t - off] : 0;
        __syncthreads();
        if (t < 128) sb[t] += v;
        __syncthreads();
    }
    // exclusive prefix for this block
    __shared__ int bexc;
    if (t == (int)blockIdx.x) bexc = sb[t] - own;
    __syncthreads();

    int base = blockIdx.x * SCB;
    int idx0 = base + t * 4;
    int4 v = make_int4(0, 0, 0, 0);
    if (idx0 + 3 < SN) v = *reinterpret_cast<const int4*>(in + idx0);
    int s = v.x + v.y + v.z + v.w;
    part[t] = s;
    __syncthreads();
    for (int off = 1; off < 256; off <<= 1) {
        int x = (t >= off) ? part[t - off] : 0;
        __syncthreads();
        part[t] += x;
        __syncthreads();
    }
    int run = bexc + part[t] - s;
    if (idx0 + 3 < SN)
        *reinterpret_cast<int4*>(baseT + idx0) =
            make_int4(run, run + v.x, run + v.x + v.y, run + v.x + v.y + v.z);
}

// K3: scatter entries into per-(sorter,bucket) contiguous chunks (R14-proven)
__global__ __launch_bounds__(256) void gc_sscat(
    const int2* __restrict__ edges, const float* __restrict__ wts,
    const int* __restrict__ baseT, int2* __restrict__ slab)
{
    __shared__ int cur[NB];
    const int s = blockIdx.x;
    for (int b = threadIdx.x; b < NB; b += 256) cur[b] = baseT[b * NS + s];
    __syncthreads();
    const int e0 = s * EPS;
    for (int i = threadIdx.x; i < EPS; i += 256) {
        int2 p = edges[e0 + i];
        int wb = __float_as_int(wts[e0 + i]);
        int b = p.y >> 7;
        int pos = atomicAdd(&cur[b], 1);
        slab[pos] = make_int2(p.x | ((p.y & 127) << 16), wb);
        b = p.x >> 7;
        pos = atomicAdd(&cur[b], 1);
        slab[pos] = make_int2(p.y | ((p.x & 127) << 16), wb);
    }
}

// K4: per-bucket CSR build from the contiguous bucket region (R14-proven)
__global__ __launch_bounds__(256) void gc_csr(
    const int* __restrict__ baseT, const int2* __restrict__ slab,
    int* __restrict__ row_start, unsigned int* __restrict__ csr4)
{
    __shared__ int ncnt[128], ncur[128], part[128];
    const int tid = threadIdx.x;
    const int b = blockIdx.x;
    const int start = baseT[b * NS];
    const int end = (b == NB - 1) ? (2 * NE) : baseT[(b + 1) * NS];

    if (tid < 128) ncnt[tid] = 0;
    __syncthreads();

    for (int j = start + tid; j < end; j += 256)
        atomicAdd(&ncnt[(slab[j].x >> 16) & 127], 1);
    __syncthreads();

    if (tid < 128) part[tid] = ncnt[tid];
    __syncthreads();
    for (int off = 1; off < 128; off <<= 1) {
        int v = 0;
        if (tid < 128 && tid >= off) v = part[tid - off];
        __syncthreads();
        if (tid < 128) part[tid] += v;
        __syncthreads();
    }
    if (tid < 128) {
        int st = start + part[tid] - ncnt[tid];
        int n = b * 128 + tid;
        if (n < NN) row_start[n] = st;
        ncur[tid] = st;
    }
    if (b == 0 && tid == 0) row_start[NN] = 2 * NE;
    __syncthreads();

    for (int j = start + tid; j < end; j += 256) {
        int2 en = slab[j];
        int dl = (en.x >> 16) & 127;
        unsigned int hb =
            (unsigned int)__half_as_ushort(__float2half_rn(__int_as_float(en.y))) << 16;
        int pos = atomicAdd(&ncur[dl], 1);
        csr4[pos] = (unsigned int)(en.x & 0xffff) | hb;
    }
}

// K5a: pack W (fp32 row-major [k][n]) into MFMA B-fragment order, bf16.
__global__ __launch_bounds__(256) void gc_wfrag(
    const float* __restrict__ Wm, unsigned short* __restrict__ wf)
{
    int t = blockIdx.x * 256 + threadIdx.x;      // 16384 total
    int j    = t & 7;
    int lane = (t >> 3) & 63;
    int nt   = (t >> 9) & 7;
    int ki   = t >> 12;
    int k = ki * 32 + (lane >> 4) * 8 + j;
    int n = nt * 16 + (lane & 15);
    wf[t] = bf16rne(Wm[k * D + n]);
}

// K5b: XW = X @ W via MFMA 16x16x32 bf16, ROW-major output (R14-proven).
__global__ __launch_bounds__(256) void gc_gemm_mfma(
    const float* __restrict__ X, const unsigned short* __restrict__ wf,
    unsigned short* __restrict__ dst)
{
    const int lane = threadIdx.x & 63;
    const int wave = threadIdx.x >> 6;
    const int rbase = blockIdx.x * 64 + wave * 16;
    const int r  = lane & 15;
    const int kb = lane >> 4;

    f32x4 acc[8];
    #pragma unroll
    for (int i = 0; i < 8; ++i) acc[i] = f32x4{0.f, 0.f, 0.f, 0.f};

    const bf16x8* wfv = reinterpret_cast<const bf16x8*>(wf);
    const int row = rbase + r;
    const bool rok = row < NN;

    #pragma unroll
    for (int ki = 0; ki < 4; ++ki) {
        float4 a0 = make_float4(0.f, 0.f, 0.f, 0.f);
        float4 a1 = make_float4(0.f, 0.f, 0.f, 0.f);
        if (rok) {
            const float4* xp = reinterpret_cast<const float4*>(
                X + (size_t)row * D + ki * 32 + kb * 8);
            a0 = xp[0];
            a1 = xp[1];
        }
        bf16x8 af;
        af[0] = (short)bf16rne(a0.x); af[1] = (short)bf16rne(a0.y);
        af[2] = (short)bf16rne(a0.z); af[3] = (short)bf16rne(a0.w);
        af[4] = (short)bf16rne(a1.x); af[5] = (short)bf16rne(a1.y);
        af[6] = (short)bf16rne(a1.z); af[7] = (short)bf16rne(a1.w);
        #pragma unroll
        for (int nt = 0; nt < 8; ++nt) {
            bf16x8 bf = wfv[(ki * 8 + nt) * 64 + lane];
            acc[nt] = __builtin_amdgcn_mfma_f32_16x16x32_bf16(af, bf, acc[nt], 0, 0, 0);
        }
    }

    const int orow0 = rbase + kb * 4;
    #pragma unroll
    for (int nt = 0; nt < 8; ++nt) {
        #pragma unroll
        for (int reg = 0; reg < 4; ++reg) {
            int orow = orow0 + reg;
            if (orow < NN)
                dst[(size_t)orow * D + nt * 16 + r] = bf16rne(acc[nt][reg]);
        }
    }
}

// K6: gather bf16 rows, wave per node, 16x unroll (deep MLP) + 4x + scalar.
__global__ __launch_bounds__(256) void gc_gather4(
    const int* __restrict__ row_start, const unsigned int* __restrict__ csr4,
    const unsigned int* __restrict__ F, float* __restrict__ out)
{
    int wid  = (blockIdx.x * 256 + threadIdx.x) >> 6;
    unsigned int lane = threadIdx.x & 63;
    if (wid >= NN) return;
    int j   = row_start[wid];
    int end = row_start[wid + 1];
    v2f acc = {0.f, 0.f};
    float dw = 0.f;
    for (; j + 16 <= end; j += 16) {
        unsigned int e[16], v[16];
        #pragma unroll
        for (int q = 0; q < 16; ++q) e[q] = csr4[j + q];
        #pragma unroll
        for (int q = 0; q < 16; ++q) v[q] = F[((e[q] & 0xffffu) << 6) | lane];
        #pragma unroll
        for (int q = 0; q < 16; ++q) {
            float w = wdec(e[q]);
            acc += w * v2f{bf_lo(v[q]), bf_hi(v[q])};
            dw += w;
        }
    }
    for (; j + 4 <= end; j += 4) {
        unsigned int e0 = csr4[j],     e1 = csr4[j + 1];
        unsigned int e2 = csr4[j + 2], e3 = csr4[j + 3];
        unsigned int v0 = F[((e0 & 0xffffu) << 6) | lane];
        unsigned int v1 = F[((e1 & 0xffffu) << 6) | lane];
        unsigned int v2 = F[((e2 & 0xffffu) << 6) | lane];
        unsigned int v3 = F[((e3 & 0xffffu) << 6) | lane];
        float w0 = wdec(e0), w1 = wdec(e1), w2 = wdec(e2), w3 = wdec(e3);
        acc += w0 * v2f{bf_lo(v0), bf_hi(v0)};
        acc += w1 * v2f{bf_lo(v1), bf_hi(v1)};
        acc += w2 * v2f{bf_lo(v2), bf_hi(v2)};
        acc += w3 * v2f{bf_lo(v3), bf_hi(v3)};
        dw += (w0 + w1) + (w2 + w3);
    }
    for (; j < end; ++j) {
        unsigned int e0 = csr4[j];
        unsigned int v0 = F[((e0 & 0xffffu) << 6) | lane];
        float w0 = wdec(e0);
        acc += w0 * v2f{bf_lo(v0), bf_hi(v0)};
        dw += w0;
    }
    float inv = dw > 0.f ? 1.f / dw : 0.f;
    float2 r; r.x = acc.x * inv; r.y = acc.y * inv;
    reinterpret_cast<float2*>(out)[(size_t)wid * 64 + lane] = r;
}

// ======================= fallback path (fp32, small ws) ====================
__global__ __launch_bounds__(256) void gc_hist(
    const int2* __restrict__ edges, int* __restrict__ counts)
{
    int e = blockIdx.x * 256 + threadIdx.x;
    if (e >= NE) return;
    int2 p = edges[e];
    atomicAdd(counts + p.x, 1);
    atomicAdd(counts + p.y, 1);
}

__global__ __launch_bounds__(1024) void gc_scan(
    const int* __restrict__ counts, int* __restrict__ row_start,
    int* __restrict__ cursor)
{
    const int CHUNK = (NN + 1023) / 1024;
    __shared__ int part[1024];
    int t = threadIdx.x;
    int lo = t * CHUNK, hi = min(lo + CHUNK, NN);
    int s = 0;
    for (int i = lo; i < hi; ++i) s += counts[i];
    part[t] = s;
    __syncthreads();
    for (int off = 1; off < 1024; off <<= 1) {
        int v = (t >= off) ? part[t - off] : 0;
        __syncthreads();
        part[t] += v;
        __syncthreads();
    }
    int run = part[t] - s;
    for (int i = lo; i < hi; ++i) {
        int c = counts[i];
        row_start[i] = run;
        cursor[i]    = run;
        run += c;
    }
    if (t == 1023) row_start[NN] = part[1023];
}

__global__ __launch_bounds__(256) void gc_fill8(
    const int2* __restrict__ edges, const float* __restrict__ wts,
    int* __restrict__ cursor, int2* __restrict__ csr)
{
    int e = blockIdx.x * 256 + threadIdx.x;
    if (e >= NE) return;
    int2 p = edges[e];
    int wb = __float_as_int(wts[e]);
    int pos = atomicAdd(cursor + p.y, 1);
    csr[pos] = make_int2(p.x, wb);
    pos = atomicAdd(cursor + p.x, 1);
    csr[pos] = make_int2(p.y, wb);
}

__global__ __launch_bounds__(256) void gc_gather_f32(
    const int* __restrict__ row_start, const int2* __restrict__ csr,
    const float* __restrict__ F, float* __restrict__ out)
{
    int wid  = (blockIdx.x * 256 + threadIdx.x) >> 6;
    int lane = threadIdx.x & 63;
    if (wid >= NN) return;
    int j   = row_start[wid];
    int end = row_start[wid + 1];
    const float2* F2 = reinterpret_cast<const float2*>(F);
    float ax = 0.f, ay = 0.f, dw = 0.f;
    for (; j < end; ++j) {
        int2  cw = csr[j];
        float w  = __int_as_float(cw.y);
        float2 xv = F2[(size_t)cw.x * 64 + lane];
        ax = fmaf(w, xv.x, ax);
        ay = fmaf(w, xv.y, ay);
        dw += w;
    }
    float inv = dw > 0.f ? 1.f / dw : 0.f;
    float2 r; r.x = ax * inv; r.y = ay * inv;
    reinterpret_cast<float2*>(out)[(size_t)wid * 64 + lane] = r;
}

__global__ __launch_bounds__(256) void gc_gemm_f32(
    const float* __restrict__ src, float* __restrict__ dst,
    const float* __restrict__ Wm)
{
    __shared__ float Ws[D * D];
    __shared__ float axs[16 * D];
    const int tid = threadIdx.x;
    const int col = tid & 127;
    const int ty  = tid >> 7;
    const int rbase = blockIdx.x * 16;

    const float4* W4  = reinterpret_cast<const float4*>(Wm);
    float4*       Ws4 = reinterpret_cast<float4*>(Ws);
    #pragma unroll
    for (int i = 0; i < 16; ++i) Ws4[tid + i * 256] = W4[tid + i * 256];

    const float4* A4   = reinterpret_cast<const float4*>(src + (size_t)rbase * D);
    float4*       axs4 = reinterpret_cast<float4*>(axs);
    #pragma unroll
    for (int i = 0; i < 2; ++i) axs4[tid + i * 256] = A4[tid + i * 256];
    __syncthreads();

    float acc[8];
    #pragma unroll
    for (int i = 0; i < 8; ++i) acc[i] = 0.f;

    for (int k = 0; k < D; ++k) {
        float wv = Ws[k * D + col];
        #pragma unroll
        for (int i = 0; i < 8; ++i)
            acc[i] = fmaf(axs[(ty * 8 + i) * D + k], wv, acc[i]);
    }

    #pragma unroll
    for (int i = 0; i < 8; ++i)
        dst[(size_t)(rbase + ty * 8 + i) * D + col] = acc[i];
}

extern "C" void kernel_launch(void* const* d_in, const int* in_sizes, int n_in,
                              void* d_out, int out_size, void* d_ws, size_t ws_size,
                              hipStream_t stream) {
    const float* X     = (const float*)d_in[0];
    const int2*  edges = (const int2*)d_in[1];
    const float* wts   = (const float*)d_in[2];
    const float* Wm    = (const float*)d_in[3];
    float* out = (float*)d_out;
    char*  ws  = (char*)d_ws;

    const int eblocks = (NE + 255) / 256;

    if (ws_size >= NEED_A) {
        int2* slab  = (int2*)(ws + OFF_SLAB);
        unsigned int* csr4 = (unsigned int*)(ws + OFF_CSR4);
        int*  histT = (int*)(ws + OFF_HIST);
        int*  baseT = (int*)(ws + OFF_BASE);
        int*  bsum  = (int*)(ws + OFF_BSUM);
        int*  row   = (int*)(ws + OFF_ROW);
        unsigned short* wf = (unsigned short*)(ws + OFF_WF);
        unsigned short* xw = (unsigned short*)(ws + OFF_XW);   // aliases dead slab

        gc_shist<<<NS, 256, 0, stream>>>(edges, histT);
        gc_scanA<<<NSB, 256, 0, stream>>>(histT, bsum);
        gc_scanC<<<NSB, 256, 0, stream>>>(histT, bsum, baseT);
        gc_sscat<<<NS, 256, 0, stream>>>(edges, wts, baseT, slab);
        gc_wfrag<<<64, 256, 0, stream>>>(Wm, wf);
        gc_csr<<<NB, 256, 0, stream>>>(baseT, slab, row, csr4);
        gc_gemm_mfma<<<(NN + 63) / 64, 256, 0, stream>>>(X, wf, xw);  // overwrites slab
        gc_gather4<<<(NN * 64 + 255) / 256, 256, 0, stream>>>(
            row, csr4, (const unsigned int*)xw, out);
    } else {
        int*  counts    = (int*) (ws + OFF_CNT);
        int*  row_start = (int*) (ws + OFF_ROWF);
        int*  cursor    = (int*) (ws + OFF_CUR);
        int2* csr       = (int2*)(ws + OFF_CSR8);

        hipMemsetAsync(counts, 0, NN * sizeof(int), stream);
        gc_hist<<<eblocks, 256, 0, stream>>>(edges, counts);
        gc_scan<<<1, 1024, 0, stream>>>(counts, row_start, cursor);
        gc_fill8<<<eblocks, 256, 0, stream>>>(edges, wts, cursor, csr);
        gc_gather_f32<<<(NN * 64 + 255) / 256, 256, 0, stream>>>(row_start, csr, X, out);
        gc_gemm_f32<<<NN / 16, 256, 0, stream>>>(out, out, Wm);
    }
}